// Round 3
// baseline (73.185 us; speedup 1.0000x reference)
//
#include <hip/hip_runtime.h>
#include <stdint.h>

#define N_ 8192
#define D_ 64
#define B_ 2
#define M_ 3
#define ROWS 32      // output rows per block
#define SRX 35       // staged X rows r0 .. r0+34
#define PAD 68       // LDS inner pad: stride%32==4 -> 2-way max (free), 16B aligned
#define NDOT 35      // dot columns jj = 0..34 (local)

typedef __attribute__((ext_vector_type(8))) short short8;
typedef __attribute__((ext_vector_type(8))) __bf16 bf16x8;
typedef __attribute__((ext_vector_type(4))) float f32x4;

// float -> bf16 (round-to-nearest-even) on raw bits
__device__ __forceinline__ short f2bf(float f) {
    uint32_t u = __builtin_bit_cast(uint32_t, f);
    u = (u + 0x7FFFu + ((u >> 16) & 1u)) >> 16;
    return (short)(u & 0xFFFFu);
}

__device__ __forceinline__ f32x4 mfma16(short8 a, short8 b, f32x4 c) {
    return __builtin_amdgcn_mfma_f32_16x16x32_bf16(
        __builtin_bit_cast(bf16x8, a), __builtin_bit_cast(bf16x8, b), c, 0, 0, 0);
}

// ============================================================================
// Fused kernel, latency-optimized:
//  - 512 blocks x 256 threads, 2 blocks/CU resident -> cross-block phase
//    overlap hides barrier-serialized latency (was 1 block/CU).
//  - Wf dot-loads hoisted to registers BEFORE the X-stage barrier (T14):
//    __syncthreads drains vmcnt anyway, so phase 2 becomes pure FMA.
//  - b in the high grid bit: b=0/b=1 twins (bid, bid+256) share an XCD L2
//    under round-robin dispatch -> Wf columns fetched once per XCD pair.
// ============================================================================
__global__ __launch_bounds__(256, 2) void smf_fused(
    const float* __restrict__ X,    // [B][N][64]
    const float* __restrict__ Wg,   // [64][64]
    const float* __restrict__ bg,   // [64]
    const float* __restrict__ Wf,   // [3][64][N]
    const float* __restrict__ bfv,  // [3][N]
    float* __restrict__ Out)        // [B][N][64]
{
    __shared__ __align__(16) float Xs[SRX][PAD];     // 9.5 KB
    __shared__ float ddP[M_][NDOT + 1][2];           // d-dot halves
    __shared__ float ooP[M_][NDOT + 1][2];           // o-dot halves; idx jj holds o[jj-1]

    const int tid = threadIdx.x;
    const int bid = blockIdx.x;
    const int b   = bid >> 8;
    const int r0  = (bid & 255) * ROWS;
    const float* Xb = X + (size_t)b * N_ * D_;

    // ---- phase 0: ISSUE Wf dot-loads early (registers, no LDS dependency) --
    const bool isDot = (tid < M_ * NDOT * 2);   // 210 threads
    int m = 0, jj = 0, dh = 0;
    float wfv[32];
    float pbf = 0.f;
    if (isDot) {
        m  = tid / (NDOT * 2);
        int r = tid - m * (NDOT * 2);
        jj = r >> 1;              // local col 0..34
        dh = r & 1;               // d half
        int j = (r0 + jj) & (N_ - 1);
        const float* wp = Wf + ((size_t)(m * D_ + dh * 32)) * N_ + j;
        #pragma unroll
        for (int i = 0; i < 32; ++i) wfv[i] = wp[(size_t)i * N_];
        pbf = bfv[m * N_ + j];
    }

    // ---- phase 1a: stage X rows r0..r0+34 (coalesced f32x4) ----
    for (int p = tid; p < SRX * 16; p += 256) {
        int rr = p >> 4, c4 = p & 15;
        int row = (r0 + rr) & (N_ - 1);
        f32x4 v = *(const f32x4*)(Xb + (size_t)row * D_ + c4 * 4);
        *(f32x4*)&Xs[rr][c4 * 4] = v;
    }

    // ---- phase 1b: Wg B-fragments + bg (global, overlaps staging) ----
    const int w  = tid >> 6;          // wave 0..3
    const int l  = tid & 63;
    const int lo = l & 15;
    const int q  = l >> 4;
    const int rt  = w >> 1;           // row-tile 0..1 (16 rows each)
    const int ct0 = (w & 1) * 2;      // first of two col-tiles

    short8 Bf[2][2];                  // [kh][ci]
    #pragma unroll
    for (int kh = 0; kh < 2; ++kh) {
        #pragma unroll
        for (int ci = 0; ci < 2; ++ci) {
            short8 s;
            #pragma unroll
            for (int jn = 0; jn < 8; ++jn) {
                int k = kh * 32 + q * 8 + jn;       // B[k][n], n = lane&15
                s[jn] = f2bf(Wg[k * 64 + (ct0 + ci) * 16 + lo]);
            }
            Bf[kh][ci] = s;
        }
    }
    const float bgv0 = bg[(ct0 + 0) * 16 + lo];
    const float bgv1 = bg[(ct0 + 1) * 16 + lo];

    __syncthreads();   // X staged; wfv/pbf also drained by this barrier

    // ---- phase 2: dots = pure FMA now (Wf already in registers) ----
    if (isDot) {
        float ad = dh ? 0.f : pbf;    // dd[jj] = X[jj]  .col[jj] + bf[jj]
        float ao = dh ? 0.f : pbf;    // ooP[jj] = X[jj-1].col[jj] + bf[jj] (= o[jj-1])
        const int jb = jj ? jj - 1 : 0;   // jj==0 result unused
        #pragma unroll
        for (int dg = 0; dg < 8; ++dg) {
            f32x4 xa = *(const f32x4*)&Xs[jj][dh * 32 + dg * 4];
            f32x4 xb = *(const f32x4*)&Xs[jb][dh * 32 + dg * 4];
            #pragma unroll
            for (int t = 0; t < 4; ++t) {
                ad += xa[t] * wfv[dg * 4 + t];
                ao += xb[t] * wfv[dg * 4 + t];
            }
        }
        ddP[m][jj][dh] = ad;
        ooP[m][jj][dh] = ao;
    }
    __syncthreads();   // dots visible

    // ---- phase 3: chain coefficients for local row iL ----
    const int iL = rt * 16 + lo;
    #define DDv(mm, i) (ddP[mm][i][0] + ddP[mm][i][1])
    #define OOv(mm, i) (ooP[mm][(i) + 1][0] + ooP[mm][(i) + 1][1])
    float D0  = DDv(0, iL),     O0  = OOv(0, iL);
    float D0p = DDv(0, iL + 1), O0p = OOv(0, iL + 1);
    float D0q = DDv(0, iL + 2), O0q = OOv(0, iL + 2);
    float D1  = DDv(1, iL),     O1  = OOv(1, iL);
    float D1p = DDv(1, iL + 1), O1p = OOv(1, iL + 1);
    float D2  = DDv(2, iL),     O2  = OOv(2, iL);
    float ck0 = D2 * D1 * D0;
    float ck1 = D2 * D1 * O0 + D2 * O1 * D0p + O2 * D1p * D0p;
    float ck2 = D2 * O1 * O0p + O2 * D1p * O0p + O2 * O1p * D0q;
    float ck3 = O2 * O1p * O0q;
    float csum = ck0 + ck1 + ck2 + ck3;
    float ck[4] = {ck0, ck1, ck2, ck3};

    // ---- Y = sum_k c_k * X[iL+k] in A-frag layout -> 2 col-tiles of MFMA ----
    f32x4 acc0 = (f32x4){0.f, 0.f, 0.f, 0.f};
    f32x4 acc1 = (f32x4){0.f, 0.f, 0.f, 0.f};
    #pragma unroll
    for (int kh = 0; kh < 2; ++kh) {
        int cbase = kh * 32 + q * 8;
        f32x4 ya = (f32x4){0.f, 0.f, 0.f, 0.f};
        f32x4 yb = (f32x4){0.f, 0.f, 0.f, 0.f};
        #pragma unroll
        for (int k = 0; k < 4; ++k) {
            f32x4 xa = *(const f32x4*)&Xs[iL + k][cbase];
            f32x4 xb = *(const f32x4*)&Xs[iL + k][cbase + 4];
            #pragma unroll
            for (int t = 0; t < 4; ++t) { ya[t] += ck[k] * xa[t]; yb[t] += ck[k] * xb[t]; }
        }
        short8 A;
        #pragma unroll
        for (int jn = 0; jn < 4; ++jn) { A[jn] = f2bf(ya[jn]); A[4 + jn] = f2bf(yb[jn]); }
        acc0 = mfma16(A, Bf[kh][0], acc0);
        acc1 = mfma16(A, Bf[kh][1], acc1);
    }

    // ---- epilogue: C/D layout col=lane&15, row=q*4+r; csum via shuffle ----
    #pragma unroll
    for (int r = 0; r < 4; ++r) {
        int orow = q * 4 + r;
        float cs = __shfl(csum, orow);        // lane orow (q=0) holds row rt*16+orow
        size_t rowbase = ((size_t)b * N_ + (r0 + rt * 16 + orow)) * D_;
        Out[rowbase + (ct0 + 0) * 16 + lo] = acc0[r] + cs * bgv0;
        Out[rowbase + (ct0 + 1) * 16 + lo] = acc1[r] + cs * bgv1;
    }
}

extern "C" void kernel_launch(void* const* d_in, const int* in_sizes, int n_in,
                              void* d_out, int out_size, void* d_ws, size_t ws_size,
                              hipStream_t stream) {
    const float* X   = (const float*)d_in[0];
    const float* Wg  = (const float*)d_in[1];
    const float* bg  = (const float*)d_in[2];
    const float* Wf  = (const float*)d_in[3];
    const float* bfv = (const float*)d_in[4];
    float* Out = (float*)d_out;

    dim3 grid(B_ * (N_ / ROWS));   // 512 blocks -> 2 blocks/CU
    dim3 block(256);
    hipLaunchKernelGGL(smf_fused, grid, block, 0, stream, X, Wg, bg, Wf, bfv, Out);
}

// Round 4
// 71.441 us; speedup vs baseline: 1.0244x; 1.0244x over previous
//
#include <hip/hip_runtime.h>
#include <stdint.h>

#define N_ 8192
#define D_ 64
#define B_ 2
#define M_ 3
#define ROWS 64      // output rows per block
#define SRX 67       // staged X rows r0 .. r0+66
#define PAD 68       // LDS inner pad: stride%32==4 -> 2-way max (free), 16B aligned
#define NDOT 67      // dot columns jj = 0..66 (local)

typedef __attribute__((ext_vector_type(8))) short short8;
typedef __attribute__((ext_vector_type(8))) __bf16 bf16x8;
typedef __attribute__((ext_vector_type(4))) float f32x4;

// float -> bf16 (round-to-nearest-even) on raw bits
__device__ __forceinline__ short f2bf(float f) {
    uint32_t u = __builtin_bit_cast(uint32_t, f);
    u = (u + 0x7FFFu + ((u >> 16) & 1u)) >> 16;
    return (short)(u & 0xFFFFu);
}

__device__ __forceinline__ f32x4 mfma16(short8 a, short8 b, f32x4 c) {
    return __builtin_amdgcn_mfma_f32_16x16x32_bf16(
        __builtin_bit_cast(bf16x8, a), __builtin_bit_cast(bf16x8, b), c, 0, 0, 0);
}

// ============================================================================
// Round-2 base (best measured: 70.73) + ONE change: T14 issue-early hoist of
// the phase-2 Wf gather into registers before the X-staging loop. The
// __syncthreads guarding Xs drains vmcnt anyway, so the Wf values are free in
// VGPRs at barrier 1 and the dot phase becomes pure FMA (one exposed
// cold-HBM latency round instead of two).
//  - 256 blocks x 512 threads, 64 output rows/block, 1 block/CU.
//  - b in high grid bit: b=0/b=1 twins (bid, bid+128) share an XCD L2
//    under round-robin dispatch -> Wf columns fetched once per XCD pair.
// ============================================================================
__global__ __launch_bounds__(512, 2) void smf_fused(
    const float* __restrict__ X,    // [B][N][64]
    const float* __restrict__ Wg,   // [64][64]
    const float* __restrict__ bg,   // [64]
    const float* __restrict__ Wf,   // [3][64][N]
    const float* __restrict__ bfv,  // [3][N]
    float* __restrict__ Out)        // [B][N][64]
{
    __shared__ __align__(16) float Xs[SRX][PAD];     // 18.2 KB
    __shared__ float ddP[M_][NDOT + 1][2];           // d-dot halves
    __shared__ float ooP[M_][NDOT + 1][2];           // o-dot halves; idx jj holds o[jj-1]

    const int tid = threadIdx.x;
    const int bid = blockIdx.x;
    const int b   = bid >> 7;
    const int r0  = (bid & 127) * ROWS;
    const float* Xb = X + (size_t)b * N_ * D_;

    // ---- phase 0: ISSUE Wf dot-loads early (registers, no LDS dependency) --
    const bool isDot = (tid < M_ * NDOT * 2);   // 402 threads
    int m = 0, jj = 0, dh = 0;
    float wfv[32];
    float pbf = 0.f;
    if (isDot) {
        m  = tid / (NDOT * 2);
        int r = tid - m * (NDOT * 2);
        jj = r >> 1;              // local col 0..66
        dh = r & 1;               // d half
        int j = (r0 + jj) & (N_ - 1);
        const float* wp = Wf + ((size_t)(m * D_ + dh * 32)) * N_ + j;
        #pragma unroll
        for (int i = 0; i < 32; ++i) wfv[i] = wp[(size_t)i * N_];
        pbf = bfv[m * N_ + j];
    }

    // ---- phase 1a: stage X rows r0..r0+66 (coalesced f32x4) ----
    for (int p = tid; p < SRX * 16; p += 512) {
        int rr = p >> 4, c4 = p & 15;
        int row = (r0 + rr) & (N_ - 1);
        f32x4 v = *(const f32x4*)(Xb + (size_t)row * D_ + c4 * 4);
        *(f32x4*)&Xs[rr][c4 * 4] = v;
    }

    // ---- phase 1b: Wg B-fragments + bg (global, overlaps staging) ----
    const int w  = tid >> 6;          // wave 0..7
    const int l  = tid & 63;
    const int lo = l & 15;
    const int q  = l >> 4;
    const int rt  = w >> 1;           // row-tile 0..3 (16 rows each)
    const int ct0 = (w & 1) * 2;      // first of two col-tiles

    short8 Bf[2][2];                  // [kh][ci]
    #pragma unroll
    for (int kh = 0; kh < 2; ++kh) {
        #pragma unroll
        for (int ci = 0; ci < 2; ++ci) {
            short8 s;
            #pragma unroll
            for (int jn = 0; jn < 8; ++jn) {
                int k = kh * 32 + q * 8 + jn;       // B[k][n], n = lane&15
                s[jn] = f2bf(Wg[k * 64 + (ct0 + ci) * 16 + lo]);
            }
            Bf[kh][ci] = s;
        }
    }
    const float bgv0 = bg[(ct0 + 0) * 16 + lo];
    const float bgv1 = bg[(ct0 + 1) * 16 + lo];

    __syncthreads();   // X staged; wfv/pbf also drained by this barrier

    // ---- phase 2: dots = pure FMA now (Wf already in registers) ----
    if (isDot) {
        float ad = dh ? 0.f : pbf;    // dd[jj]  = X[jj]  .col[jj] + bf[jj]
        float ao = dh ? 0.f : pbf;    // ooP[jj] = X[jj-1].col[jj] + bf[jj] (= o[jj-1])
        const int jb = jj ? jj - 1 : 0;   // jj==0 result unused
        #pragma unroll
        for (int dg = 0; dg < 8; ++dg) {
            f32x4 xa = *(const f32x4*)&Xs[jj][dh * 32 + dg * 4];
            f32x4 xb = *(const f32x4*)&Xs[jb][dh * 32 + dg * 4];
            #pragma unroll
            for (int t = 0; t < 4; ++t) {
                ad += xa[t] * wfv[dg * 4 + t];
                ao += xb[t] * wfv[dg * 4 + t];
            }
        }
        ddP[m][jj][dh] = ad;
        ooP[m][jj][dh] = ao;
    }
    __syncthreads();   // dots visible

    // ---- phase 3: chain coefficients for local row iL ----
    const int iL = rt * 16 + lo;
    #define DDv(mm, i) (ddP[mm][i][0] + ddP[mm][i][1])
    #define OOv(mm, i) (ooP[mm][(i) + 1][0] + ooP[mm][(i) + 1][1])
    float D0  = DDv(0, iL),     O0  = OOv(0, iL);
    float D0p = DDv(0, iL + 1), O0p = OOv(0, iL + 1);
    float D0q = DDv(0, iL + 2), O0q = OOv(0, iL + 2);
    float D1  = DDv(1, iL),     O1  = OOv(1, iL);
    float D1p = DDv(1, iL + 1), O1p = OOv(1, iL + 1);
    float D2  = DDv(2, iL),     O2  = OOv(2, iL);
    float ck0 = D2 * D1 * D0;
    float ck1 = D2 * D1 * O0 + D2 * O1 * D0p + O2 * D1p * D0p;
    float ck2 = D2 * O1 * O0p + O2 * D1p * O0p + O2 * O1p * D0q;
    float ck3 = O2 * O1p * O0q;
    float csum = ck0 + ck1 + ck2 + ck3;
    float ck[4] = {ck0, ck1, ck2, ck3};

    // ---- Y = sum_k c_k * X[iL+k] in A-frag layout -> 2 col-tiles of MFMA ----
    f32x4 acc0 = (f32x4){0.f, 0.f, 0.f, 0.f};
    f32x4 acc1 = (f32x4){0.f, 0.f, 0.f, 0.f};
    #pragma unroll
    for (int kh = 0; kh < 2; ++kh) {
        int cbase = kh * 32 + q * 8;
        f32x4 ya = (f32x4){0.f, 0.f, 0.f, 0.f};
        f32x4 yb = (f32x4){0.f, 0.f, 0.f, 0.f};
        #pragma unroll
        for (int k = 0; k < 4; ++k) {
            f32x4 xa = *(const f32x4*)&Xs[iL + k][cbase];
            f32x4 xb = *(const f32x4*)&Xs[iL + k][cbase + 4];
            #pragma unroll
            for (int t = 0; t < 4; ++t) { ya[t] += ck[k] * xa[t]; yb[t] += ck[k] * xb[t]; }
        }
        short8 A;
        #pragma unroll
        for (int jn = 0; jn < 4; ++jn) { A[jn] = f2bf(ya[jn]); A[4 + jn] = f2bf(yb[jn]); }
        acc0 = mfma16(A, Bf[kh][0], acc0);
        acc1 = mfma16(A, Bf[kh][1], acc1);
    }

    // ---- epilogue: C/D layout col=lane&15, row=q*4+r; csum via shuffle ----
    #pragma unroll
    for (int r = 0; r < 4; ++r) {
        int orow = q * 4 + r;
        float cs = __shfl(csum, orow);        // lane orow (q=0) holds row rt*16+orow
        size_t rowbase = ((size_t)b * N_ + (r0 + rt * 16 + orow)) * D_;
        Out[rowbase + (ct0 + 0) * 16 + lo] = acc0[r] + cs * bgv0;
        Out[rowbase + (ct0 + 1) * 16 + lo] = acc1[r] + cs * bgv1;
    }
}

extern "C" void kernel_launch(void* const* d_in, const int* in_sizes, int n_in,
                              void* d_out, int out_size, void* d_ws, size_t ws_size,
                              hipStream_t stream) {
    const float* X   = (const float*)d_in[0];
    const float* Wg  = (const float*)d_in[1];
    const float* bg  = (const float*)d_in[2];
    const float* Wf  = (const float*)d_in[3];
    const float* bfv = (const float*)d_in[4];
    float* Out = (float*)d_out;

    dim3 grid(B_ * (N_ / ROWS));   // 256 blocks, 1/CU, 8 waves/CU
    dim3 block(512);
    hipLaunchKernelGGL(smf_fused, grid, block, 0, stream, X, Wg, bg, Wf, bfv, Out);
}

// Round 5
// 69.894 us; speedup vs baseline: 1.0471x; 1.0221x over previous
//
#include <hip/hip_runtime.h>
#include <stdint.h>

#define N_ 8192
#define D_ 64
#define B_ 2
#define M_ 3
#define ROWS 64      // output rows per block
#define SRX 67       // staged X rows r0 .. r0+66
#define PAD 68       // LDS inner pad: stride%32==4 -> 2-way max (free), 16B aligned
#define NDOT 67      // dot columns jj = 0..66 (local)

typedef __attribute__((ext_vector_type(8))) short short8;
typedef __attribute__((ext_vector_type(8))) __bf16 bf16x8;
typedef __attribute__((ext_vector_type(4))) float f32x4;

// float -> bf16 (round-to-nearest-even) on raw bits
__device__ __forceinline__ short f2bf(float f) {
    uint32_t u = __builtin_bit_cast(uint32_t, f);
    u = (u + 0x7FFFu + ((u >> 16) & 1u)) >> 16;
    return (short)(u & 0xFFFFu);
}

__device__ __forceinline__ f32x4 mfma16(short8 a, short8 b, f32x4 c) {
    return __builtin_amdgcn_mfma_f32_16x16x32_bf16(
        __builtin_bit_cast(bf16x8, a), __builtin_bit_cast(bf16x8, b), c, 0, 0, 0);
}

// ============================================================================
// Round-2 base (best measured: 70.73) + ONE change: bijective XCD-aware
// blockIdx swizzle (T1). Physical bid -> XCD is bid%8 round-robin; decoding
// logical L = (bid&7)*32 + (bid>>3) gives each XCD 32 consecutive logical
// blocks = one contiguous 16-wide k-chunk x both b values. Consecutive-k
// blocks AND b=0/b=1 twins (which read IDENTICAL Wf columns) now share an
// XCD L2 -> each Wf line fetched ~1.06x chip-wide instead of up to ~2.5x.
//  - 256 blocks x 512 threads, 64 output rows/block, 1 block/CU.
// ============================================================================
__global__ __launch_bounds__(512, 2) void smf_fused(
    const float* __restrict__ X,    // [B][N][64]
    const float* __restrict__ Wg,   // [64][64]
    const float* __restrict__ bg,   // [64]
    const float* __restrict__ Wf,   // [3][64][N]
    const float* __restrict__ bfv,  // [3][N]
    float* __restrict__ Out)        // [B][N][64]
{
    __shared__ __align__(16) float Xs[SRX][PAD];     // 18.2 KB
    __shared__ float ddP[M_][NDOT + 1][2];           // d-dot halves
    __shared__ float ooP[M_][NDOT + 1][2];           // o-dot halves; idx jj holds o[jj-1]

    const int tid = threadIdx.x;
    const int bid = blockIdx.x;
    const int Lid = (bid & 7) * 32 + (bid >> 3);     // bijective XCD swizzle
    const int b   = Lid & 1;                         // b-twins adjacent -> same XCD
    const int r0  = (Lid >> 1) * ROWS;               // k contiguous within XCD chunk
    const float* Xb = X + (size_t)b * N_ * D_;

    // ---- phase 1a: stage X rows r0..r0+66 (coalesced f32x4) ----
    for (int p = tid; p < SRX * 16; p += 512) {
        int rr = p >> 4, c4 = p & 15;
        int row = (r0 + rr) & (N_ - 1);
        f32x4 v = *(const f32x4*)(Xb + (size_t)row * D_ + c4 * 4);
        *(f32x4*)&Xs[rr][c4 * 4] = v;
    }

    // ---- phase 1b: Wg B-fragments + bg (pure global, overlaps staging) ----
    const int w  = tid >> 6;          // wave 0..7
    const int l  = tid & 63;
    const int lo = l & 15;
    const int q  = l >> 4;
    const int rt  = w >> 1;           // row-tile 0..3 (16 rows each)
    const int ct0 = (w & 1) * 2;      // first of two col-tiles

    short8 Bf[2][2];                  // [kh][ci]
    #pragma unroll
    for (int kh = 0; kh < 2; ++kh) {
        #pragma unroll
        for (int ci = 0; ci < 2; ++ci) {
            short8 s;
            #pragma unroll
            for (int jn = 0; jn < 8; ++jn) {
                int k = kh * 32 + q * 8 + jn;       // B[k][n], n = lane&15
                s[jn] = f2bf(Wg[k * 64 + (ct0 + ci) * 16 + lo]);
            }
            Bf[kh][ci] = s;
        }
    }
    const float bgv0 = bg[(ct0 + 0) * 16 + lo];
    const float bgv1 = bg[(ct0 + 1) * 16 + lo];

    __syncthreads();   // X staged

    // ---- phase 2: dots. thread -> (m, jj, dh); 3*67*2 = 402 active ----
    if (tid < M_ * NDOT * 2) {
        int m  = tid / (NDOT * 2);
        int r  = tid - m * (NDOT * 2);
        int jj = r >> 1;              // local col 0..66
        int dh = r & 1;               // d half
        int j  = (r0 + jj) & (N_ - 1);
        const float* wp = Wf + ((size_t)(m * D_ + dh * 32)) * N_ + j;
        float bfval = bfv[m * N_ + j];
        float ad = dh ? 0.f : bfval;  // dd[jj]   = X[jj]  .col[jj] + bf[jj]
        float ao = dh ? 0.f : bfval;  // ooP[jj]  = X[jj-1].col[jj] + bf[jj]  (= o[jj-1])
        const int jb = jj ? jj - 1 : 0;   // jj==0 result unused
        #pragma unroll
        for (int dg = 0; dg < 8; ++dg) {
            float w0 = wp[(size_t)(dg * 4 + 0) * N_];
            float w1 = wp[(size_t)(dg * 4 + 1) * N_];
            float w2 = wp[(size_t)(dg * 4 + 2) * N_];
            float w3 = wp[(size_t)(dg * 4 + 3) * N_];
            f32x4 xa = *(const f32x4*)&Xs[jj][dh * 32 + dg * 4];
            f32x4 xb = *(const f32x4*)&Xs[jb][dh * 32 + dg * 4];
            ad += xa[0] * w0 + xa[1] * w1 + xa[2] * w2 + xa[3] * w3;
            ao += xb[0] * w0 + xb[1] * w1 + xb[2] * w2 + xb[3] * w3;
        }
        ddP[m][jj][dh] = ad;
        ooP[m][jj][dh] = ao;
    }
    __syncthreads();   // dots visible

    // ---- phase 3: chain coefficients for local row iL ----
    const int iL = rt * 16 + lo;
    #define DDv(mm, i) (ddP[mm][i][0] + ddP[mm][i][1])
    #define OOv(mm, i) (ooP[mm][(i) + 1][0] + ooP[mm][(i) + 1][1])
    float D0  = DDv(0, iL),     O0  = OOv(0, iL);
    float D0p = DDv(0, iL + 1), O0p = OOv(0, iL + 1);
    float D0q = DDv(0, iL + 2), O0q = OOv(0, iL + 2);
    float D1  = DDv(1, iL),     O1  = OOv(1, iL);
    float D1p = DDv(1, iL + 1), O1p = OOv(1, iL + 1);
    float D2  = DDv(2, iL),     O2  = OOv(2, iL);
    float ck0 = D2 * D1 * D0;
    float ck1 = D2 * D1 * O0 + D2 * O1 * D0p + O2 * D1p * D0p;
    float ck2 = D2 * O1 * O0p + O2 * D1p * O0p + O2 * O1p * D0q;
    float ck3 = O2 * O1p * O0q;
    float csum = ck0 + ck1 + ck2 + ck3;
    float ck[4] = {ck0, ck1, ck2, ck3};

    // ---- Y = sum_k c_k * X[iL+k] in A-frag layout -> 2 col-tiles of MFMA ----
    f32x4 acc0 = (f32x4){0.f, 0.f, 0.f, 0.f};
    f32x4 acc1 = (f32x4){0.f, 0.f, 0.f, 0.f};
    #pragma unroll
    for (int kh = 0; kh < 2; ++kh) {
        int cbase = kh * 32 + q * 8;
        f32x4 ya = (f32x4){0.f, 0.f, 0.f, 0.f};
        f32x4 yb = (f32x4){0.f, 0.f, 0.f, 0.f};
        #pragma unroll
        for (int k = 0; k < 4; ++k) {
            f32x4 xa = *(const f32x4*)&Xs[iL + k][cbase];
            f32x4 xb = *(const f32x4*)&Xs[iL + k][cbase + 4];
            #pragma unroll
            for (int t = 0; t < 4; ++t) { ya[t] += ck[k] * xa[t]; yb[t] += ck[k] * xb[t]; }
        }
        short8 A;
        #pragma unroll
        for (int jn = 0; jn < 4; ++jn) { A[jn] = f2bf(ya[jn]); A[4 + jn] = f2bf(yb[jn]); }
        acc0 = mfma16(A, Bf[kh][0], acc0);
        acc1 = mfma16(A, Bf[kh][1], acc1);
    }

    // ---- epilogue: C/D layout col=lane&15, row=q*4+r; csum via shuffle ----
    #pragma unroll
    for (int r = 0; r < 4; ++r) {
        int orow = q * 4 + r;
        float cs = __shfl(csum, orow);        // lane orow (q=0) holds row rt*16+orow
        size_t rowbase = ((size_t)b * N_ + (r0 + rt * 16 + orow)) * D_;
        Out[rowbase + (ct0 + 0) * 16 + lo] = acc0[r] + cs * bgv0;
        Out[rowbase + (ct0 + 1) * 16 + lo] = acc1[r] + cs * bgv1;
    }
}

extern "C" void kernel_launch(void* const* d_in, const int* in_sizes, int n_in,
                              void* d_out, int out_size, void* d_ws, size_t ws_size,
                              hipStream_t stream) {
    const float* X   = (const float*)d_in[0];
    const float* Wg  = (const float*)d_in[1];
    const float* bg  = (const float*)d_in[2];
    const float* Wf  = (const float*)d_in[3];
    const float* bfv = (const float*)d_in[4];
    float* Out = (float*)d_out;

    dim3 grid(B_ * (N_ / ROWS));   // 256 blocks, 1/CU, 8 waves/CU
    dim3 block(512);
    hipLaunchKernelGGL(smf_fused, grid, block, 0, stream, X, Wg, bg, Wf, bfv, Out);
}